// Round 15
// baseline (759.143 us; speedup 1.0000x reference)
//
#include <hip/hip_runtime.h>

// F2FConv3d on MI355X.
// V17 = V14 (best, 655.6us) + DUAL ACCUMULATOR CHAINS: the 36 MFMAs run as two
// independent 18-deep chains (even chunks -> accE, odd -> accO, interleaved issue),
// merged in the epilogue. V14's single 36-deep dependent chain exposed ~36x~25cy of
// MFMA latency per iter with only 2 waves/SIMD to hide it; V6 (2x18 chains, 3
// waves/SIMD) had 3x less exposure — this closes that gap at +16 AGPRs
// (~228 -> ~244 total regs, still 2 waves/SIMD under (256,2); no spill risk since
// the budget is 256 here, not V7's 170 cap). Everything else identical to V14.
//
// K ordering per 32x32x16 chunk c (0..35): kb = c>>2, ci = (c&3)*16 + (lane>>5)*8 + j.
// A: row = lane&31 (channel). C/D (m74/m101): col = lane&31 (texture),
// row = (reg&3)+8*(reg>>2)+4*(lane>>5). Facet = 4 adjacent lanes -> DPP qsum.
// Stats: lane q=lane&3 takes channel slice qp==q -> exact (disjoint, no overcount).
//
// Pipeline (= V6 template): 3-buffer rotation, SINGLE barrier/iter (stage(t) targets
// buffer read at t-1), depth-2 counted vmcnt, NEVER 0 in loop. Ladder for
// [stage:6][stores:4]: prologue 6/10, steady 14, tail 14/8. X staged via
// global_load_lds (linear dest, swizzled global src g' = g ^ (tt&15)) ->
// conflict-free swizzled b128 reads.

typedef _Float16 half8  __attribute__((ext_vector_type(8)));
typedef _Float16 h2     __attribute__((ext_vector_type(2)));
typedef __fp16   fp16x2 __attribute__((ext_vector_type(2)));
typedef float    f32x4  __attribute__((ext_vector_type(4)));
typedef float    f32x16 __attribute__((ext_vector_type(16)));

#define NQUADS  25000    // 100000 groups / 4 per block-iter
#define FFACETS 400000
#define GRID1   512      // 2 blocks/CU x 256 CUs
#define LDSP    18752    // per buffer: X[0,16384) | BARY[16384,18688) | NTEX[18688,18752)

#define WAITV(N) asm volatile("s_waitcnt vmcnt(" #N ")" ::: "memory")
#define WAITL0() asm volatile("s_waitcnt lgkmcnt(0)" ::: "memory")
#define FENCE()  asm volatile("" ::: "memory")

union H8 { h2 h[4]; half8 v; };

static __device__ __forceinline__ h2 pkrtz(float a, float b) {
    fp16x2 r = __builtin_amdgcn_cvt_pkrtz(a, b);
    return __builtin_bit_cast(h2, r);
}

// facet sum over the 4 adjacent lanes of a quad — VALU-pipe DPP, no DS traffic
static __device__ __forceinline__ float qsum(float s) {
    s += __builtin_bit_cast(float, __builtin_amdgcn_mov_dpp(
             __builtin_bit_cast(int, s), 0xB1, 0xF, 0xF, true));   // quad_perm [1,0,3,2]
    s += __builtin_bit_cast(float, __builtin_amdgcn_mov_dpp(
             __builtin_bit_cast(int, s), 0x4E, 0xF, 0xF, true));   // quad_perm [2,3,0,1]
    return s;
}

static __device__ __forceinline__ void gload16(const void* g, void* l) {
    __builtin_amdgcn_global_load_lds((const __attribute__((address_space(1))) void*)g,
                                     (__attribute__((address_space(3))) void*)l, 16, 0, 0);
}

// ---- kernel 1: swizzle W (fp32 [64][64][9]) -> 32x32x16 A-fragment order, zero stats
__global__ __launch_bounds__(256) void prep_kernel(const float* __restrict__ W,
                                                   _Float16* __restrict__ wswz,
                                                   float* __restrict__ stats) {
    int idx = blockIdx.x * 256 + threadIdx.x;
    if (idx < 36864) {
        int j    = idx & 7;
        int lane = (idx >> 3) & 63;
        int wc   = (idx >> 9) & 1;        // channel half
        int c    = idx >> 10;             // chunk 0..35
        int o    = wc * 32 + (lane & 31);
        int i    = (c & 3) * 16 + (lane >> 5) * 8 + j;
        int kb   = c >> 2;
        wswz[idx] = (_Float16)W[(o * 64 + i) * 9 + kb];
    }
    if (idx < 128) stats[idx] = 0.0f;
}

// ---- kernel 2: fused GEMM + facet mean + bias + ReLU + BN-stat accumulation
__global__ __launch_bounds__(256, 2) void pass1_kernel(
    const float* __restrict__ X, const float* __restrict__ BARY,
    const _Float16* __restrict__ WSWZ, const float* __restrict__ BIAS,
    const int* __restrict__ NTEX, float* __restrict__ OUT,
    float* __restrict__ stats) {

    __shared__ __align__(16) char ldsbuf[3 * LDSP];
    __shared__ float sl_s[128];
    __shared__ float sl_s2[128];
    __shared__ float sbias[64];

    const int tid  = threadIdx.x;
    const int wave = tid >> 6;
    const int lane = tid & 63;
    const int wc   = wave >> 1;   // channel half (0: ch 0-31, 1: ch 32-63)
    const int wt   = wave & 1;    // texture half (32 of the 64 textures)
    const int t    = lane & 31;   // texture within the wave's 32 (MFMA column)
    const int hi   = lane >> 5;
    const int q    = lane & 3;

    // bias -> LDS (all waves redundantly: uniform vmem count), 1 global + 1 ds_write
    sbias[lane] = BIAS[lane];
    WAITL0();

    // A-operand: 36 chunks x 4 VGPR = 144 AGPRs, resident whole kernel
    half8 wf[36];
#pragma unroll
    for (int c = 0; c < 36; ++c)
        wf[c] = *(const half8*)(WSWZ + ((size_t)(c * 2 + wc) * 64 + lane) * 8);

    // ---- stage-side: linear LDS dest, XOR-swizzled global src (granule ^= tt&15)
    int xsg[4];
#pragma unroll
    for (int i = 0; i < 4; ++i) {
        const int tt = wave * 16 + i * 4 + (lane >> 4);          // texture 0..63 in quad
        xsg[i] = tt * 256 + (((lane & 15) ^ (tt & 15)) << 4);
    }
    const int xd = wave * 4096 + lane * 16;                      // linear dest
    const char* Xb  = (const char*)X;
    const char* BAb = (const char*)BARY;
    const char* NTb = (const char*)NTEX;

    // ---- read-side: swizzled granule -> 2 lanes/granule = conflict-free b128
    int xr[8];
#pragma unroll
    for (int ciq = 0; ciq < 4; ++ciq)
#pragma unroll
        for (int jj = 0; jj < 2; ++jj)
            xr[ciq * 2 + jj] = (wt * 32 + t) * 256 +
                               (((ciq * 4 + hi * 2 + jj) ^ (lane & 15)) << 4);
    const int bco = 16384 + (wt * 2 + (t >> 4)) * 576 + (lane & 15) * 36;
    const int nco = 18688 + wt * 32 + ((t >> 2) << 2);

    float sacc[4]  = {0.f, 0.f, 0.f, 0.f};
    float s2acc[4] = {0.f, 0.f, 0.f, 0.f};

    const int b = blockIdx.x;
    const int n = (NQUADS - 1 - b) / GRID1 + 1;                  // quads for this block

    // 6 vmem ops per wave per STAGE (4 X quarters + bary group + ntex quad)
    auto STAGE = [&](char* S, int u) {
        const char* xs = Xb + (size_t)u * 16384;
        FENCE();
        gload16(xs + xsg[0], S + xd);
        gload16(xs + xsg[1], S + xd + 1024);
        gload16(xs + xsg[2], S + xd + 2048);
        gload16(xs + xsg[3], S + xd + 3072);
        if (lane < 36) gload16(BAb + (size_t)u * 2304 + wave * 576 + lane * 16,
                               S + 16384 + wave * 576 + lane * 16);
        if (lane < 1)  gload16(NTb + (size_t)u * 64 + wave * 16, S + 18688 + wave * 16);
        FENCE();
    };

    // ITER: [barrier][read L: 8 b128 X + 9 b32 bary + nt][stage into S]
    //       [pack][36 MFMA as 2x18 independent chains][qsum EPI + stats + 4 stores]
    auto ITER = [&](const char* L, char* S, int u, int upre, bool do_stage) {
        __builtin_amdgcn_s_barrier();      // caller did WAITV: stage(u) landed for all waves
        FENCE();
        f32x4 r[8];
#pragma unroll
        for (int k = 0; k < 8; ++k) r[k] = *(const f32x4*)(L + xr[k]);
        float bF[9];
#pragma unroll
        for (int k = 0; k < 9; ++k) bF[k] = *(const float*)(L + bco + k * 4);
        const int nt = *(const int*)(L + nco);

        if (do_stage) STAGE(S, upre);      // flies across 2 iterations

        // pack x (16 pkrtz) and bary (9 pkrtz)
        h2 xh[16], bh[9];
#pragma unroll
        for (int k = 0; k < 8; ++k) {
            xh[k * 2]     = pkrtz(r[k][0], r[k][1]);
            xh[k * 2 + 1] = pkrtz(r[k][2], r[k][3]);
        }
#pragma unroll
        for (int k = 0; k < 9; ++k) bh[k] = pkrtz(bF[k], bF[k]);
        const float rc = __builtin_amdgcn_rcpf((float)nt);       // exact for pow2 counts

        // ---- 36 MFMAs as TWO independent 18-chains (even c -> accE, odd c -> accO)
        f32x16 accE = {};
        f32x16 accO = {};
        __builtin_amdgcn_s_setprio(1);
#pragma unroll
        for (int c = 0; c < 36; c += 2) {
            const h2 bkE = bh[c >> 2];
            const int xbE = (c & 3) * 4;
            H8 bfE;
            bfE.h[0] = xh[xbE + 0] * bkE;  bfE.h[1] = xh[xbE + 1] * bkE;
            bfE.h[2] = xh[xbE + 2] * bkE;  bfE.h[3] = xh[xbE + 3] * bkE;
            accE = __builtin_amdgcn_mfma_f32_32x32x16_f16(wf[c], bfE.v, accE, 0, 0, 0);
            const h2 bkO = bh[(c + 1) >> 2];
            const int xbO = ((c + 1) & 3) * 4;
            H8 bfO;
            bfO.h[0] = xh[xbO + 0] * bkO;  bfO.h[1] = xh[xbO + 1] * bkO;
            bfO.h[2] = xh[xbO + 2] * bkO;  bfO.h[3] = xh[xbO + 3] * bkO;
            accO = __builtin_amdgcn_mfma_f32_32x32x16_f16(wf[c + 1], bfO.v, accO, 0, 0, 0);
        }
        __builtin_amdgcn_s_setprio(0);

        // bias read AFTER the MFMA loop (short liveness; from LDS)
        f32x4 bias4[4];
#pragma unroll
        for (int qp = 0; qp < 4; ++qp)
            bias4[qp] = *(const f32x4*)&sbias[wc * 32 + hi * 4 + qp * 8];

        // ---- facet mean + bias + ReLU (rows: reg=qp*4+j -> ch = wc*32 + 4hi + 8qp + j)
        f32x4 vq[4];
#pragma unroll
        for (int qp = 0; qp < 4; ++qp)
#pragma unroll
            for (int j = 0; j < 4; ++j) {
                float s = qsum(accE[qp * 4 + j] + accO[qp * 4 + j]);
                s = s * rc + bias4[qp][j];
                vq[qp][j] = s > 0.f ? s : 0.f;
            }

        // stats: lane q takes slice qp==q (disjoint across the quad -> no overcount)
#pragma unroll
        for (int j = 0; j < 4; ++j) {
            float p = vq[0][j];
            p = (q == 1) ? vq[1][j] : p;
            p = (q == 2) ? vq[2][j] : p;
            p = (q == 3) ? vq[3][j] : p;
            sacc[j]  += p;
            s2acc[j] += p * p;
        }

        const int f = u * 16 + wt * 8 + (t >> 2);
        if ((lane & 3) == 0) {
            float* op = OUT + (size_t)f * 64 + wc * 32 + hi * 4;
            *(f32x4*)(op)      = vq[0];
            *(f32x4*)(op + 8)  = vq[1];
            *(f32x4*)(op + 16) = vq[2];
            *(f32x4*)(op + 24) = vq[3];
        }
    };

    char* B0 = ldsbuf;
    char* B1 = ldsbuf + LDSP;
    char* B2 = ldsbuf + 2 * LDSP;

    // ---- software pipeline: 3-buffer rotation, counted vmcnt ([stage:6][stores:4])
    STAGE(B0, b);
    STAGE(B1, b + GRID1);
    WAITV(6);  ITER(B0, B2, b,         b + 2 * GRID1, true);   // drains bias+wf+stage0
    WAITV(10); ITER(B1, B0, b + GRID1, b + 3 * GRID1, true);
    char *rd = B2, *st = B1, *ot = B0;
    int tI = 2;
    for (; tI < n - 2; ++tI) {
        WAITV(14);
        ITER(rd, st, b + tI * GRID1, b + (tI + 2) * GRID1, true);
        char* tmp = ot; ot = st; st = rd; rd = tmp;
    }
    WAITV(14); ITER(rd, st, b + tI * GRID1, 0, false);
    { char* tmp = ot; ot = st; st = rd; rd = tmp; } ++tI;
    WAITV(8);  ITER(rd, st, b + tI * GRID1, 0, false);

    // ---- stats: reduce over the 8 facet-quads per wave (lane bits 2..4), then LDS+atomics
#pragma unroll
    for (int j = 0; j < 4; ++j) {
        float s = sacc[j], s2 = s2acc[j];
        s  += __shfl_xor(s, 4);   s  += __shfl_xor(s, 8);   s  += __shfl_xor(s, 16);
        s2 += __shfl_xor(s2, 4);  s2 += __shfl_xor(s2, 8);  s2 += __shfl_xor(s2, 16);
        if (((lane >> 2) & 7) == 0) {
            const int idx = wt * 64 + wc * 32 + hi * 4 + q * 8 + j;
            sl_s[idx]  = s;
            sl_s2[idx] = s2;
        }
    }
    __syncthreads();
    if (tid < 64)        atomicAdd(&stats[tid], sl_s[tid] + sl_s[tid + 64]);
    else if (tid < 128)  atomicAdd(&stats[tid], sl_s2[tid - 64] + sl_s2[tid]);
}

// ---- kernel 3: in-place batch-norm normalize on OUT
__global__ __launch_bounds__(256) void pass3_kernel(float* __restrict__ OUT,
    const float* __restrict__ stats, const float* __restrict__ gamma,
    const float* __restrict__ beta) {
    const int tid = threadIdx.x;
    const size_t l = (size_t)blockIdx.x * 256 + tid;
    const int c0 = ((int)l & 15) * 4;     // grid*256 is a multiple of 16 -> constant per thread
    float mu[4], sc[4], be[4];
    const float invF = 1.0f / (float)FFACETS;
#pragma unroll
    for (int u = 0; u < 4; ++u) {
        int ch = c0 + u;
        float m  = stats[ch] * invF;
        float va = stats[64 + ch] * invF - m * m;
        mu[u] = m;
        sc[u] = rsqrtf(va + 1e-3f) * gamma[ch];
        be[u] = beta[ch];
    }
    const size_t n4 = (size_t)FFACETS * 16;
    for (size_t i = l; i < n4; i += (size_t)gridDim.x * 256) {
        f32x4 v = ((f32x4*)OUT)[i];
#pragma unroll
        for (int u = 0; u < 4; ++u)
            v[u] = (v[u] - mu[u]) * sc[u] + be[u];
        ((f32x4*)OUT)[i] = v;
    }
}

extern "C" void kernel_launch(void* const* d_in, const int* in_sizes, int n_in,
                              void* d_out, int out_size, void* d_ws, size_t ws_size,
                              hipStream_t stream) {
    const float* X     = (const float*)d_in[0];
    const float* BARY  = (const float*)d_in[1];
    const float* W     = (const float*)d_in[2];
    const float* BIAS  = (const float*)d_in[3];
    const float* GAMMA = (const float*)d_in[4];
    const float* BETA  = (const float*)d_in[5];
    const int*   NTEX  = (const int*)d_in[6];
    float* OUT = (float*)d_out;

    _Float16* wswz = (_Float16*)d_ws;                       // 73728 B
    float* stats   = (float*)((char*)d_ws + 73728);         // 128 floats

    prep_kernel<<<144, 256, 0, stream>>>(W, wswz, stats);
    pass1_kernel<<<GRID1, 256, 0, stream>>>(X, BARY, wswz, BIAS, NTEX, OUT, stats);
    pass3_kernel<<<2048, 256, 0, stream>>>(OUT, stats, GAMMA, BETA);
}

// Round 16
// 651.048 us; speedup vs baseline: 1.1660x; 1.1660x over previous
//
#include <hip/hip_runtime.h>

// F2FConv3d on MI355X.
// V14 (FINAL, best measured: 655.6us): 32x32x16 MFMA structure. Wave (wc=wave>>1,
// wt=wave&1) owns a 32ch x 32tex output tile; block processes 4 groups (64 tex) per
// iter. Per-texture VALU and DS are half of the 16x16 variant (B-build amortized
// over 32 ch); MFMA cyc/FLOP -20% (8cy/32k). wf A-frags = 36 x half8 = 144 AGPRs ->
// 2 waves/SIMD. Dual-acc variant (V17) spills (304 regs > 256, FETCH +100MB);
// 3-wave K-split variant (V15, 657.4) pays its occupancy gain back in xchg overhead.
//
// K ordering per 32x32x16 chunk c (0..35): kb = c>>2, ci = (c&3)*16 + (lane>>5)*8 + j.
// A: row = lane&31 (channel). C/D (m74/m101): col = lane&31 (texture),
// row = (reg&3)+8*(reg>>2)+4*(lane>>5). Facet = 4 adjacent lanes -> DPP qsum (VALU
// pipe, no DS). Stats: lane q=lane&3 takes channel slice qp==q -> exact, no overcount.
//
// Pipeline (= V6 template, proven over 10 rounds): 3-buffer rotation, SINGLE
// barrier/iter (stage(t) targets the buffer read at t-1), depth-2 counted vmcnt,
// NEVER 0 in the loop. Ladder for [stage:6][stores:4]: prologue 6/10, steady 14,
// tail 14/8. X staged via global_load_lds (linear LDS dest, XOR-swizzled global
// src g' = g ^ (tt&15), rule 21) -> conflict-free swizzled ds_read_b128
// (2 lanes/granule). SQ_LDS_BANK_CONFLICT measured 0.

typedef _Float16 half8  __attribute__((ext_vector_type(8)));
typedef _Float16 h2     __attribute__((ext_vector_type(2)));
typedef __fp16   fp16x2 __attribute__((ext_vector_type(2)));
typedef float    f32x4  __attribute__((ext_vector_type(4)));
typedef float    f32x16 __attribute__((ext_vector_type(16)));

#define NQUADS  25000    // 100000 groups / 4 per block-iter
#define FFACETS 400000
#define GRID1   512      // 2 blocks/CU x 256 CUs
#define LDSP    18752    // per buffer: X[0,16384) | BARY[16384,18688) | NTEX[18688,18752)

#define WAITV(N) asm volatile("s_waitcnt vmcnt(" #N ")" ::: "memory")
#define WAITL0() asm volatile("s_waitcnt lgkmcnt(0)" ::: "memory")
#define FENCE()  asm volatile("" ::: "memory")

union H8 { h2 h[4]; half8 v; };

static __device__ __forceinline__ h2 pkrtz(float a, float b) {
    fp16x2 r = __builtin_amdgcn_cvt_pkrtz(a, b);
    return __builtin_bit_cast(h2, r);
}

// facet sum over the 4 adjacent lanes of a quad — VALU-pipe DPP, no DS traffic
static __device__ __forceinline__ float qsum(float s) {
    s += __builtin_bit_cast(float, __builtin_amdgcn_mov_dpp(
             __builtin_bit_cast(int, s), 0xB1, 0xF, 0xF, true));   // quad_perm [1,0,3,2]
    s += __builtin_bit_cast(float, __builtin_amdgcn_mov_dpp(
             __builtin_bit_cast(int, s), 0x4E, 0xF, 0xF, true));   // quad_perm [2,3,0,1]
    return s;
}

static __device__ __forceinline__ void gload16(const void* g, void* l) {
    __builtin_amdgcn_global_load_lds((const __attribute__((address_space(1))) void*)g,
                                     (__attribute__((address_space(3))) void*)l, 16, 0, 0);
}

// ---- kernel 1: swizzle W (fp32 [64][64][9]) -> 32x32x16 A-fragment order, zero stats
__global__ __launch_bounds__(256) void prep_kernel(const float* __restrict__ W,
                                                   _Float16* __restrict__ wswz,
                                                   float* __restrict__ stats) {
    int idx = blockIdx.x * 256 + threadIdx.x;
    if (idx < 36864) {
        int j    = idx & 7;
        int lane = (idx >> 3) & 63;
        int wc   = (idx >> 9) & 1;        // channel half
        int c    = idx >> 10;             // chunk 0..35
        int o    = wc * 32 + (lane & 31);
        int i    = (c & 3) * 16 + (lane >> 5) * 8 + j;
        int kb   = c >> 2;
        wswz[idx] = (_Float16)W[(o * 64 + i) * 9 + kb];
    }
    if (idx < 128) stats[idx] = 0.0f;
}

// ---- kernel 2: fused GEMM + facet mean + bias + ReLU + BN-stat accumulation
__global__ __launch_bounds__(256, 2) void pass1_kernel(
    const float* __restrict__ X, const float* __restrict__ BARY,
    const _Float16* __restrict__ WSWZ, const float* __restrict__ BIAS,
    const int* __restrict__ NTEX, float* __restrict__ OUT,
    float* __restrict__ stats) {

    __shared__ __align__(16) char ldsbuf[3 * LDSP];
    __shared__ float sl_s[128];
    __shared__ float sl_s2[128];
    __shared__ float sbias[64];

    const int tid  = threadIdx.x;
    const int wave = tid >> 6;
    const int lane = tid & 63;
    const int wc   = wave >> 1;   // channel half (0: ch 0-31, 1: ch 32-63)
    const int wt   = wave & 1;    // texture half (32 of the 64 textures)
    const int t    = lane & 31;   // texture within the wave's 32 (MFMA column)
    const int hi   = lane >> 5;
    const int q    = lane & 3;

    // bias -> LDS (all waves redundantly: uniform vmem count), 1 global + 1 ds_write
    sbias[lane] = BIAS[lane];
    WAITL0();

    // A-operand: 36 chunks x 4 VGPR = 144 AGPRs, resident whole kernel
    half8 wf[36];
#pragma unroll
    for (int c = 0; c < 36; ++c)
        wf[c] = *(const half8*)(WSWZ + ((size_t)(c * 2 + wc) * 64 + lane) * 8);

    // ---- stage-side: linear LDS dest, XOR-swizzled global src (granule ^= tt&15)
    int xsg[4];
#pragma unroll
    for (int i = 0; i < 4; ++i) {
        const int tt = wave * 16 + i * 4 + (lane >> 4);          // texture 0..63 in quad
        xsg[i] = tt * 256 + (((lane & 15) ^ (tt & 15)) << 4);
    }
    const int xd = wave * 4096 + lane * 16;                      // linear dest
    const char* Xb  = (const char*)X;
    const char* BAb = (const char*)BARY;
    const char* NTb = (const char*)NTEX;

    // ---- read-side: swizzled granule -> 2 lanes/granule = conflict-free b128
    int xr[8];
#pragma unroll
    for (int ciq = 0; ciq < 4; ++ciq)
#pragma unroll
        for (int jj = 0; jj < 2; ++jj)
            xr[ciq * 2 + jj] = (wt * 32 + t) * 256 +
                               (((ciq * 4 + hi * 2 + jj) ^ (lane & 15)) << 4);
    const int bco = 16384 + (wt * 2 + (t >> 4)) * 576 + (lane & 15) * 36;
    const int nco = 18688 + wt * 32 + ((t >> 2) << 2);

    float sacc[4]  = {0.f, 0.f, 0.f, 0.f};
    float s2acc[4] = {0.f, 0.f, 0.f, 0.f};

    const int b = blockIdx.x;
    const int n = (NQUADS - 1 - b) / GRID1 + 1;                  // quads for this block

    // 6 vmem ops per wave per STAGE (4 X quarters + bary group + ntex quad)
    auto STAGE = [&](char* S, int u) {
        const char* xs = Xb + (size_t)u * 16384;
        FENCE();
        gload16(xs + xsg[0], S + xd);
        gload16(xs + xsg[1], S + xd + 1024);
        gload16(xs + xsg[2], S + xd + 2048);
        gload16(xs + xsg[3], S + xd + 3072);
        if (lane < 36) gload16(BAb + (size_t)u * 2304 + wave * 576 + lane * 16,
                               S + 16384 + wave * 576 + lane * 16);
        if (lane < 1)  gload16(NTb + (size_t)u * 64 + wave * 16, S + 18688 + wave * 16);
        FENCE();
    };

    // ITER: [barrier][read L: 8 b128 X + 9 b32 bary + nt + bias][stage into S]
    //       [pack][36 MFMA single acc chain][qsum EPI + stats + 4 stores]
    auto ITER = [&](const char* L, char* S, int u, int upre, bool do_stage) {
        __builtin_amdgcn_s_barrier();      // caller did WAITV: stage(u) landed for all waves
        FENCE();
        f32x4 r[8];
#pragma unroll
        for (int k = 0; k < 8; ++k) r[k] = *(const f32x4*)(L + xr[k]);
        float bF[9];
#pragma unroll
        for (int k = 0; k < 9; ++k) bF[k] = *(const float*)(L + bco + k * 4);
        const int nt = *(const int*)(L + nco);
        f32x4 bias4[4];
#pragma unroll
        for (int qp = 0; qp < 4; ++qp)
            bias4[qp] = *(const f32x4*)&sbias[wc * 32 + hi * 4 + qp * 8];

        if (do_stage) STAGE(S, upre);      // flies across 2 iterations

        // pack x (16 pkrtz) and bary (9 pkrtz)
        h2 xh[16], bh[9];
#pragma unroll
        for (int k = 0; k < 8; ++k) {
            xh[k * 2]     = pkrtz(r[k][0], r[k][1]);
            xh[k * 2 + 1] = pkrtz(r[k][2], r[k][3]);
        }
#pragma unroll
        for (int k = 0; k < 9; ++k) bh[k] = pkrtz(bF[k], bF[k]);
        const float rc = __builtin_amdgcn_rcpf((float)nt);       // exact for pow2 counts

        // ---- 36 MFMAs, single 16-reg accumulator chain
        f32x16 acc = {};
        __builtin_amdgcn_s_setprio(1);
#pragma unroll
        for (int c = 0; c < 36; ++c) {
            const h2 bk = bh[c >> 2];
            const int xb = (c & 3) * 4;
            H8 bf;
            bf.h[0] = xh[xb + 0] * bk;  bf.h[1] = xh[xb + 1] * bk;
            bf.h[2] = xh[xb + 2] * bk;  bf.h[3] = xh[xb + 3] * bk;
            acc = __builtin_amdgcn_mfma_f32_32x32x16_f16(wf[c], bf.v, acc, 0, 0, 0);
        }
        __builtin_amdgcn_s_setprio(0);

        // ---- facet mean + bias + ReLU (rows: reg=qp*4+j -> ch = wc*32 + 4hi + 8qp + j)
        f32x4 vq[4];
#pragma unroll
        for (int qp = 0; qp < 4; ++qp)
#pragma unroll
            for (int j = 0; j < 4; ++j) {
                float s = qsum(acc[qp * 4 + j]);
                s = s * rc + bias4[qp][j];
                vq[qp][j] = s > 0.f ? s : 0.f;
            }

        // stats: lane q takes slice qp==q (disjoint across the quad -> no overcount)
#pragma unroll
        for (int j = 0; j < 4; ++j) {
            float p = vq[0][j];
            p = (q == 1) ? vq[1][j] : p;
            p = (q == 2) ? vq[2][j] : p;
            p = (q == 3) ? vq[3][j] : p;
            sacc[j]  += p;
            s2acc[j] += p * p;
        }

        const int f = u * 16 + wt * 8 + (t >> 2);
        if ((lane & 3) == 0) {
            float* op = OUT + (size_t)f * 64 + wc * 32 + hi * 4;
            *(f32x4*)(op)      = vq[0];
            *(f32x4*)(op + 8)  = vq[1];
            *(f32x4*)(op + 16) = vq[2];
            *(f32x4*)(op + 24) = vq[3];
        }
    };

    char* B0 = ldsbuf;
    char* B1 = ldsbuf + LDSP;
    char* B2 = ldsbuf + 2 * LDSP;

    // ---- software pipeline: 3-buffer rotation, counted vmcnt ([stage:6][stores:4])
    STAGE(B0, b);
    STAGE(B1, b + GRID1);
    WAITV(6);  ITER(B0, B2, b,         b + 2 * GRID1, true);   // drains bias+wf+stage0
    WAITV(10); ITER(B1, B0, b + GRID1, b + 3 * GRID1, true);
    char *rd = B2, *st = B1, *ot = B0;
    int tI = 2;
    for (; tI < n - 2; ++tI) {
        WAITV(14);
        ITER(rd, st, b + tI * GRID1, b + (tI + 2) * GRID1, true);
        char* tmp = ot; ot = st; st = rd; rd = tmp;
    }
    WAITV(14); ITER(rd, st, b + tI * GRID1, 0, false);
    { char* tmp = ot; ot = st; st = rd; rd = tmp; } ++tI;
    WAITV(8);  ITER(rd, st, b + tI * GRID1, 0, false);

    // ---- stats: reduce over the 8 facet-quads per wave (lane bits 2..4), then LDS+atomics
#pragma unroll
    for (int j = 0; j < 4; ++j) {
        float s = sacc[j], s2 = s2acc[j];
        s  += __shfl_xor(s, 4);   s  += __shfl_xor(s, 8);   s  += __shfl_xor(s, 16);
        s2 += __shfl_xor(s2, 4);  s2 += __shfl_xor(s2, 8);  s2 += __shfl_xor(s2, 16);
        if (((lane >> 2) & 7) == 0) {
            const int idx = wt * 64 + wc * 32 + hi * 4 + q * 8 + j;
            sl_s[idx]  = s;
            sl_s2[idx] = s2;
        }
    }
    __syncthreads();
    if (tid < 64)        atomicAdd(&stats[tid], sl_s[tid] + sl_s[tid + 64]);
    else if (tid < 128)  atomicAdd(&stats[tid], sl_s2[tid - 64] + sl_s2[tid]);
}

// ---- kernel 3: in-place batch-norm normalize on OUT
__global__ __launch_bounds__(256) void pass3_kernel(float* __restrict__ OUT,
    const float* __restrict__ stats, const float* __restrict__ gamma,
    const float* __restrict__ beta) {
    const int tid = threadIdx.x;
    const size_t l = (size_t)blockIdx.x * 256 + tid;
    const int c0 = ((int)l & 15) * 4;     // grid*256 is a multiple of 16 -> constant per thread
    float mu[4], sc[4], be[4];
    const float invF = 1.0f / (float)FFACETS;
#pragma unroll
    for (int u = 0; u < 4; ++u) {
        int ch = c0 + u;
        float m  = stats[ch] * invF;
        float va = stats[64 + ch] * invF - m * m;
        mu[u] = m;
        sc[u] = rsqrtf(va + 1e-3f) * gamma[ch];
        be[u] = beta[ch];
    }
    const size_t n4 = (size_t)FFACETS * 16;
    for (size_t i = l; i < n4; i += (size_t)gridDim.x * 256) {
        f32x4 v = ((f32x4*)OUT)[i];
#pragma unroll
        for (int u = 0; u < 4; ++u)
            v[u] = (v[u] - mu[u]) * sc[u] + be[u];
        ((f32x4*)OUT)[i] = v;
    }
}

extern "C" void kernel_launch(void* const* d_in, const int* in_sizes, int n_in,
                              void* d_out, int out_size, void* d_ws, size_t ws_size,
                              hipStream_t stream) {
    const float* X     = (const float*)d_in[0];
    const float* BARY  = (const float*)d_in[1];
    const float* W     = (const float*)d_in[2];
    const float* BIAS  = (const float*)d_in[3];
    const float* GAMMA = (const float*)d_in[4];
    const float* BETA  = (const float*)d_in[5];
    const int*   NTEX  = (const int*)d_in[6];
    float* OUT = (float*)d_out;

    _Float16* wswz = (_Float16*)d_ws;                       // 73728 B
    float* stats   = (float*)((char*)d_ws + 73728);         // 128 floats

    prep_kernel<<<144, 256, 0, stream>>>(W, wswz, stats);
    pass1_kernel<<<GRID1, 256, 0, stream>>>(X, BARY, wswz, BIAS, NTEX, OUT, stats);
    pass3_kernel<<<2048, 256, 0, stream>>>(OUT, stats, GAMMA, BETA);
}